// Round 3
// baseline (130.787 us; speedup 1.0000x reference)
//
#include <hip/hip_runtime.h>

// ---------------- problem constants ----------------
#define N_    8
#define IC_   128
#define OC_   128
#define HW_   68
#define M_    2048           // total tiles = 8 * 16 * 16
#define OW_   64

constexpr float BT[8][8] = {
  {1.f, 0.f, -5.25f, 0.f, 5.25f, 0.f, -1.f, 0.f},
  {0.f, 1.f, 1.f, -4.25f, -4.25f, 1.f, 1.f, 0.f},
  {0.f, -1.f, 1.f, 4.25f, -4.25f, -1.f, 1.f, 0.f},
  {0.f, 0.5f, 0.25f, -2.5f, -1.25f, 2.f, 1.f, 0.f},
  {0.f, -0.5f, 0.25f, 2.5f, -1.25f, -2.f, 1.f, 0.f},
  {0.f, 2.f, 4.f, -2.5f, -5.f, 0.5f, 1.f, 0.f},
  {0.f, -2.f, 4.f, 2.5f, -5.f, -0.5f, 1.f, 0.f},
  {0.f, -1.f, 0.f, 5.25f, 0.f, -5.25f, 0.f, 1.f}
};
constexpr float AT[4][8] = {
  {1.f, 1.f, 1.f, 1.f, 1.f, 8.f, 8.f, 0.f},
  {0.f, 1.f, -1.f, 2.f, -2.f, 4.f, -4.f, 0.f},
  {0.f, 1.f, 1.f, 4.f, 4.f, 2.f, 2.f, 0.f},
  {0.f, 1.f, -1.f, 8.f, -8.f, 1.f, -1.f, 1.f}
};

__device__ __forceinline__ float bf2f(unsigned short u) {
  union { unsigned int i; float f; } v; v.i = ((unsigned int)u) << 16; return v.f;
}
__device__ __forceinline__ unsigned short f2bf(float f) {
  union { float f; unsigned int i; } v; v.f = f;
  unsigned int r = v.i + 0x7FFFu + ((v.i >> 16) & 1u);  // RNE
  return (unsigned short)(r >> 16);
}

typedef __attribute__((ext_vector_type(8))) short short8;
typedef __attribute__((ext_vector_type(4))) float f32x4;

// ---------------- K1: input transform ----------------
// grid (cg=8, th=16, n=8), block 256 = (tw 16) x (cl 16).
#define K1_CB 16
#define K1_PS 548
__global__ __launch_bounds__(256) void k_input_tf(const float* __restrict__ x,
                                                  unsigned short* __restrict__ xt) {
  const int cg = blockIdx.x, th = blockIdx.y, n = blockIdx.z;
  const int c0 = cg * K1_CB;
  const int h0 = th * 4;
  __shared__ float xs[K1_CB * K1_PS];

  const int tid = threadIdx.x;
  for (int idx = tid; idx < K1_CB * 8 * 17; idx += 256) {
    const int ci = idx / 136;
    const int rem = idx - ci * 136;
    const int r = rem / 17;
    const int f = rem - r * 17;
    const float4 v = *reinterpret_cast<const float4*>(
        x + ((size_t)((n * IC_ + c0 + ci) * HW_ + h0 + r)) * HW_ + f * 4);
    *reinterpret_cast<float4*>(&xs[ci * K1_PS + r * 68 + f * 4]) = v;
  }
  __syncthreads();

  const int cl = tid & 15;
  const int tw = tid >> 4;
  const float* xp = &xs[cl * K1_PS];

  float t1[8][8];
#pragma unroll
  for (int a = 0; a < 8; ++a)
#pragma unroll
    for (int j = 0; j < 8; ++j) t1[a][j] = 0.f;

#pragma unroll
  for (int i = 0; i < 8; ++i) {
    const float4 v0 = *reinterpret_cast<const float4*>(xp + i * 68 + tw * 4);
    const float4 v1 = *reinterpret_cast<const float4*>(xp + i * 68 + tw * 4 + 4);
    const float r[8] = {v0.x, v0.y, v0.z, v0.w, v1.x, v1.y, v1.z, v1.w};
#pragma unroll
    for (int a = 0; a < 8; ++a) {
      const float ba = BT[a][i];
      if (ba != 0.f) {
#pragma unroll
        for (int j = 0; j < 8; ++j) t1[a][j] += ba * r[j];
      }
    }
  }

  const int m = n * 256 + th * 16 + tw;
  const size_t base = (size_t)m * 128 + c0 + cl;
#pragma unroll
  for (int a = 0; a < 8; ++a) {
#pragma unroll
    for (int b = 0; b < 8; ++b) {
      float v = 0.f;
#pragma unroll
      for (int j = 0; j < 8; ++j) {
        const float bb = BT[b][j];
        if (bb != 0.f) v += t1[a][j] * bb;
      }
      xt[(size_t)(a * 8 + b) * (M_ * 128) + base] = f2bf(v);
    }
  }
}

// ---------------- K2: weight transform to bf16 B^T ----------------
// wT[ab][oc][c] = bf16(w[oc][c][ab])
__global__ __launch_bounds__(256) void k_wt(const float* __restrict__ w,
                                            unsigned short* __restrict__ wT) {
  const int idx = blockIdx.x * 256 + threadIdx.x;  // 64*128*128
  const int c  = idx & 127;
  const int oc = (idx >> 7) & 127;
  const int ab = idx >> 14;
  wT[idx] = f2bf(w[((size_t)oc * IC_ + c) * 64 + ab]);
}

// ---------------- K3: fused batched MFMA GEMM + output transform ----------------
// grid (mb=128, ob=2), block 256 = 4 waves (1m x 4n). BM=16 tiles, BN=64 oc.
// Loops all 64 ab (b outer, a inner), folds each per-ab C-tile into the output
// transform accumulator y_acc[j][p][q]; yt never touches memory.
// Quad-buffered LDS staging, 3-deep prefetch, counted vmcnt, 1 barrier/iter.
__global__ __launch_bounds__(256) void k_gemm_out(const unsigned short* __restrict__ xt,
                                                  const unsigned short* __restrict__ wT,
                                                  const float* __restrict__ bias,
                                                  float* __restrict__ y) {
  const int mb = blockIdx.x;          // 0..127
  const int ob = blockIdx.y;          // 0..1
  const int m0 = mb * 16;
  const int oc0 = ob * 64;
  const int n  = mb >> 4;
  const int th = mb & 15;

  __shared__ unsigned short As[4][16 * 128];   // 4 x 4KB
  __shared__ unsigned short Bs[4][64 * 128];   // 4 x 16KB
  __shared__ float ys[64 * 68];                // 17.4KB

  const int tid = threadIdx.x;
  const int lane = tid & 63;
  const int wv = tid >> 6;
  const int lr = lane & 15;
  const int lg = lane >> 4;

  // stage seq-index s into buffer s&3.  seq s = b*8 + a -> ab = a*8 + b.
  // per wave: 1 A-inst + 4 B-insts = 5 outstanding vmcnt events per stage.
#define STAGE(s_) do {                                                              \
    const int ab_ = (((s_) & 7) << 3) + ((s_) >> 3);                                \
    const unsigned short* Ag_ = xt + (size_t)ab_ * (M_ * 128) + (size_t)m0 * 128;   \
    const unsigned short* Bg_ = wT + (size_t)ab_ * (128 * 128) + (size_t)oc0 * 128; \
    { const int r_ = wv * 4 + (lane >> 4);                                          \
      const int j_ = (lane & 15) ^ (r_ & 7);                                        \
      __builtin_amdgcn_global_load_lds(                                             \
        (const __attribute__((address_space(1))) void*)(Ag_ + r_ * 128 + j_ * 8),   \
        (__attribute__((address_space(3))) void*)(&As[(s_) & 3][wv * 512]), 16, 0, 0); } \
    _Pragma("unroll")                                                               \
    for (int i_ = 0; i_ < 4; ++i_) {                                                \
      const int inst_ = wv * 4 + i_;                                                \
      const int r_ = inst_ * 4 + (lane >> 4);                                       \
      const int j_ = (lane & 15) ^ (r_ & 7);                                        \
      __builtin_amdgcn_global_load_lds(                                             \
        (const __attribute__((address_space(1))) void*)(Bg_ + r_ * 128 + j_ * 8),   \
        (__attribute__((address_space(3))) void*)(&Bs[(s_) & 3][inst_ * 512]), 16, 0, 0); } \
  } while (0)

  float y_acc[4][4][4] = {};   // [j][p][q]

  STAGE(0); STAGE(1); STAGE(2);

#pragma unroll
  for (int b = 0; b < 8; ++b) {
    float u[4][4];             // [j][p]
#pragma unroll
    for (int a = 0; a < 8; ++a) {
      const int s = b * 8 + a;
      // wait for stage s (younger in flight: s+1, s+2 -> 10; tail: 5 / 0)
      if (s <= 61)      asm volatile("s_waitcnt vmcnt(10)" ::: "memory");
      else if (s == 62) asm volatile("s_waitcnt vmcnt(5)" ::: "memory");
      else              asm volatile("s_waitcnt vmcnt(0)" ::: "memory");
      __builtin_amdgcn_s_barrier();
      if (s <= 60) STAGE(s + 3);

      // ---- GEMM: 16m x 16oc x 128k for this ab ----
      const int buf = s & 3;
      f32x4 cc = (f32x4){0.f, 0.f, 0.f, 0.f};
#pragma unroll
      for (int kk = 0; kk < 4; ++kk) {
        const int arow = lr;
        const int brow = wv * 16 + lr;
        const short8 af = *reinterpret_cast<const short8*>(
            &As[buf][arow * 128 + ((kk * 4 + lg) ^ (arow & 7)) * 8]);
        const short8 bf = *reinterpret_cast<const short8*>(
            &Bs[buf][brow * 128 + ((kk * 4 + lg) ^ (brow & 7)) * 8]);
        cc = __builtin_amdgcn_mfma_f32_16x16x32_bf16(af, bf, cc, 0, 0, 0);
      }

      // ---- fold: u[j][p] (+)= AT[p][a] * cc[j] ----
#pragma unroll
      for (int j = 0; j < 4; ++j) {
        const float cv = cc[j];
#pragma unroll
        for (int p = 0; p < 4; ++p) {
          const float w_ = AT[p][a];
          if (a == 0)           u[j][p] = w_ * cv;
          else if (w_ != 0.f)   u[j][p] += w_ * cv;
        }
      }
      if (a == 7) {
#pragma unroll
        for (int q = 0; q < 4; ++q) {
          const float wq = AT[q][b];
          if (wq != 0.f) {
#pragma unroll
            for (int j = 0; j < 4; ++j)
#pragma unroll
              for (int p = 0; p < 4; ++p)
                y_acc[j][p][q] += wq * u[j][p];
          }
        }
      }
    }
  }
#undef STAGE

  // ---- epilogue: bias + coalesced write via LDS transpose staging ----
  const int oc_loc = wv * 16 + lr;
  const float bv = bias[oc0 + oc_loc];
#pragma unroll
  for (int p = 0; p < 4; ++p) {
#pragma unroll
    for (int j = 0; j < 4; ++j) {
      const int m_loc = lg * 4 + j;   // == tw
      const float4 v = {y_acc[j][p][0] + bv, y_acc[j][p][1] + bv,
                        y_acc[j][p][2] + bv, y_acc[j][p][3] + bv};
      *reinterpret_cast<float4*>(&ys[oc_loc * 68 + m_loc * 4]) = v;
    }
    __syncthreads();
#pragma unroll
    for (int it = 0; it < 4; ++it) {
      const int idx = it * 256 + tid;
      const int row = idx >> 4;       // oc-local 0..63
      const int f = idx & 15;
      const float4 v = *reinterpret_cast<const float4*>(&ys[row * 68 + f * 4]);
      *reinterpret_cast<float4*>(
          y + (((size_t)(n * OC_ + oc0 + row) * OW_) + th * 4 + p) * OW_ + f * 4) = v;
    }
    __syncthreads();
  }
}

// ---------------- launch ----------------
extern "C" void kernel_launch(void* const* d_in, const int* in_sizes, int n_in,
                              void* d_out, int out_size, void* d_ws, size_t ws_size,
                              hipStream_t stream) {
  (void)in_sizes; (void)n_in; (void)out_size; (void)ws_size;
  const float* x    = (const float*)d_in[0];
  const float* w    = (const float*)d_in[1];
  const float* bias = (const float*)d_in[2];
  float* y = (float*)d_out;

  char* ws = (char*)d_ws;
  unsigned short* xt = (unsigned short*)ws;                                 // 32 MiB
  unsigned short* wT = (unsigned short*)(ws + (size_t)32 * 1024 * 1024);    //  2 MiB

  hipLaunchKernelGGL(k_input_tf, dim3(8, 16, 8), dim3(256), 0, stream, x, xt);
  hipLaunchKernelGGL(k_wt, dim3((64 * 128 * 128) / 256), dim3(256), 0, stream, w, wT);
  hipLaunchKernelGGL(k_gemm_out, dim3(128, 2), dim3(256), 0, stream, xt, wT, bias, y);
}

// Round 5
// 122.531 us; speedup vs baseline: 1.0674x; 1.0674x over previous
//
#include <hip/hip_runtime.h>

// ---------------- problem constants ----------------
#define N_    8
#define IC_   128
#define OC_   128
#define HW_   68
#define M_    2048           // total tiles = 8 * 16 * 16
#define OW_   64

constexpr float BT[8][8] = {
  {1.f, 0.f, -5.25f, 0.f, 5.25f, 0.f, -1.f, 0.f},
  {0.f, 1.f, 1.f, -4.25f, -4.25f, 1.f, 1.f, 0.f},
  {0.f, -1.f, 1.f, 4.25f, -4.25f, -1.f, 1.f, 0.f},
  {0.f, 0.5f, 0.25f, -2.5f, -1.25f, 2.f, 1.f, 0.f},
  {0.f, -0.5f, 0.25f, 2.5f, -1.25f, -2.f, 1.f, 0.f},
  {0.f, 2.f, 4.f, -2.5f, -5.f, 0.5f, 1.f, 0.f},
  {0.f, -2.f, 4.f, 2.5f, -5.f, -0.5f, 1.f, 0.f},
  {0.f, -1.f, 0.f, 5.25f, 0.f, -5.25f, 0.f, 1.f}
};
constexpr float AT[4][8] = {
  {1.f, 1.f, 1.f, 1.f, 1.f, 8.f, 8.f, 0.f},
  {0.f, 1.f, -1.f, 2.f, -2.f, 4.f, -4.f, 0.f},
  {0.f, 1.f, 1.f, 4.f, 4.f, 2.f, 2.f, 0.f},
  {0.f, 1.f, -1.f, 8.f, -8.f, 1.f, -1.f, 1.f}
};

__device__ __forceinline__ float bf2f(unsigned short u) {
  union { unsigned int i; float f; } v; v.i = ((unsigned int)u) << 16; return v.f;
}
__device__ __forceinline__ unsigned short f2bf(float f) {
  union { float f; unsigned int i; } v; v.f = f;
  unsigned int r = v.i + 0x7FFFu + ((v.i >> 16) & 1u);  // RNE
  return (unsigned short)(r >> 16);
}

typedef __attribute__((ext_vector_type(8))) short short8;
typedef __attribute__((ext_vector_type(4))) float f32x4;

// ---------------- K1: input transform ----------------
// grid (cg=8, th=16, n=8), block 256 = (tw 16) x (cl 16).
#define K1_CB 16
#define K1_PS 548
__global__ __launch_bounds__(256) void k_input_tf(const float* __restrict__ x,
                                                  unsigned short* __restrict__ xt) {
  const int cg = blockIdx.x, th = blockIdx.y, n = blockIdx.z;
  const int c0 = cg * K1_CB;
  const int h0 = th * 4;
  __shared__ float xs[K1_CB * K1_PS];

  const int tid = threadIdx.x;
  for (int idx = tid; idx < K1_CB * 8 * 17; idx += 256) {
    const int ci = idx / 136;
    const int rem = idx - ci * 136;
    const int r = rem / 17;
    const int f = rem - r * 17;
    const float4 v = *reinterpret_cast<const float4*>(
        x + ((size_t)((n * IC_ + c0 + ci) * HW_ + h0 + r)) * HW_ + f * 4);
    *reinterpret_cast<float4*>(&xs[ci * K1_PS + r * 68 + f * 4]) = v;
  }
  __syncthreads();

  const int cl = tid & 15;
  const int tw = tid >> 4;
  const float* xp = &xs[cl * K1_PS];

  float t1[8][8];
#pragma unroll
  for (int a = 0; a < 8; ++a)
#pragma unroll
    for (int j = 0; j < 8; ++j) t1[a][j] = 0.f;

#pragma unroll
  for (int i = 0; i < 8; ++i) {
    const float4 v0 = *reinterpret_cast<const float4*>(xp + i * 68 + tw * 4);
    const float4 v1 = *reinterpret_cast<const float4*>(xp + i * 68 + tw * 4 + 4);
    const float r[8] = {v0.x, v0.y, v0.z, v0.w, v1.x, v1.y, v1.z, v1.w};
#pragma unroll
    for (int a = 0; a < 8; ++a) {
      const float ba = BT[a][i];
      if (ba != 0.f) {
#pragma unroll
        for (int j = 0; j < 8; ++j) t1[a][j] += ba * r[j];
      }
    }
  }

  const int m = n * 256 + th * 16 + tw;
  const size_t base = (size_t)m * 128 + c0 + cl;
#pragma unroll
  for (int a = 0; a < 8; ++a) {
#pragma unroll
    for (int b = 0; b < 8; ++b) {
      float v = 0.f;
#pragma unroll
      for (int j = 0; j < 8; ++j) {
        const float bb = BT[b][j];
        if (bb != 0.f) v += t1[a][j] * bb;
      }
      xt[(size_t)(a * 8 + b) * (M_ * 128) + base] = f2bf(v);
    }
  }
}

// ---------------- K2: weight transform to bf16 B^T ----------------
// wT[ab][oc][c] = bf16(w[oc][c][ab])
__global__ __launch_bounds__(256) void k_wt(const float* __restrict__ w,
                                            unsigned short* __restrict__ wT) {
  const int idx = blockIdx.x * 256 + threadIdx.x;  // 64*128*128
  const int c  = idx & 127;
  const int oc = (idx >> 7) & 127;
  const int ab = idx >> 14;
  wT[idx] = f2bf(w[((size_t)oc * IC_ + c) * 64 + ab]);
}

// ---------------- K3: batched MFMA GEMM ----------------
// per ab: C[m][oc] = sum_c A[m][c] * Bt[oc][c];  A,Bt,C bf16 (f32 accum)
// BM=128 (grid.x=16), BN=128, K=128 fully staged. 512 thr = 8 waves (4m x 2n),
// wave tile 32m x 64oc. LDS 64KB -> 2 blocks/CU. XOR-swizzle via source addr.
__global__ __launch_bounds__(512) void k_gemm(const unsigned short* __restrict__ xt,
                                              const unsigned short* __restrict__ wT,
                                              unsigned short* __restrict__ yt) {
  const int ab = blockIdx.z;
  const int m0 = blockIdx.x * 128;
  const unsigned short* Ag = xt + (size_t)ab * (M_ * 128);
  const unsigned short* Bg = wT + (size_t)ab * (128 * 128);
  unsigned short* Cg = yt + (size_t)ab * (M_ * 128);

  __shared__ unsigned short As[128 * 128];   // 32 KB, row=m
  __shared__ unsigned short Bs[128 * 128];   // 32 KB, row=oc

  const int tid = threadIdx.x;
  const int lane = tid & 63;
  const int wv = tid >> 6;

  // ---- stage A (32 wave-insts, 4/wave) and B (32, 4/wave) ----
#pragma unroll
  for (int i = 0; i < 4; ++i) {
    const int inst = wv * 4 + i;
    const int r = inst * 4 + (lane >> 4);
    const int j = (lane & 15) ^ (r & 7);
    __builtin_amdgcn_global_load_lds(
        (const __attribute__((address_space(1))) void*)(Ag + (size_t)(m0 + r) * 128 + j * 8),
        (__attribute__((address_space(3))) void*)(As + inst * 512), 16, 0, 0);
  }
#pragma unroll
  for (int i = 0; i < 4; ++i) {
    const int inst = wv * 4 + i;
    const int r = inst * 4 + (lane >> 4);
    const int j = (lane & 15) ^ (r & 7);
    __builtin_amdgcn_global_load_lds(
        (const __attribute__((address_space(1))) void*)(Bg + (size_t)r * 128 + j * 8),
        (__attribute__((address_space(3))) void*)(Bs + inst * 512), 16, 0, 0);
  }
  __syncthreads();

  // ---- compute: wave (wm 0..3, wn 0..1): 32m x 64oc ----
  const int wm = wv >> 1, wn = wv & 1;
  const int m_base = wm * 32;
  const int oc_base = wn * 64;
  const int lr = lane & 15;
  const int lg = lane >> 4;

  f32x4 acc[2][4];
#pragma unroll
  for (int mi = 0; mi < 2; ++mi)
#pragma unroll
    for (int ni = 0; ni < 4; ++ni) acc[mi][ni] = (f32x4){0.f, 0.f, 0.f, 0.f};

#pragma unroll
  for (int kk = 0; kk < 4; ++kk) {
    short8 af[2], bf[4];
#pragma unroll
    for (int mi = 0; mi < 2; ++mi) {
      const int row = m_base + mi * 16 + lr;
      const int chunk = (kk * 4 + lg) ^ (row & 7);
      af[mi] = *reinterpret_cast<const short8*>(&As[row * 128 + chunk * 8]);
    }
#pragma unroll
    for (int ni = 0; ni < 4; ++ni) {
      const int row = oc_base + ni * 16 + lr;
      const int chunk = (kk * 4 + lg) ^ (row & 7);
      bf[ni] = *reinterpret_cast<const short8*>(&Bs[row * 128 + chunk * 8]);
    }
#pragma unroll
    for (int mi = 0; mi < 2; ++mi)
#pragma unroll
      for (int ni = 0; ni < 4; ++ni)
        acc[mi][ni] = __builtin_amdgcn_mfma_f32_16x16x32_bf16(af[mi], bf[ni], acc[mi][ni], 0, 0, 0);
  }

  // ---- epilogue: C[row][col], col=lane&15, row=(lane>>4)*4+reg ----
#pragma unroll
  for (int mi = 0; mi < 2; ++mi) {
#pragma unroll
    for (int ni = 0; ni < 4; ++ni) {
#pragma unroll
      for (int j = 0; j < 4; ++j) {
        const int row = m0 + m_base + mi * 16 + lg * 4 + j;
        const int col = oc_base + ni * 16 + lr;
        Cg[(size_t)row * 128 + col] = f2bf(acc[mi][ni][j]);
      }
    }
  }
}

// ---------------- K4: output transform + bias ----------------
// grid (og=4, th=16, n=8), block 512 = (tw 16) x (ocl 32).
#define K4_PS 260
__global__ __launch_bounds__(512) void k_output_tf(const unsigned short* __restrict__ yt,
                                                   const float* __restrict__ bias,
                                                   float* __restrict__ y) {
  const int og = blockIdx.x, th = blockIdx.y, n = blockIdx.z;
  const int oc0 = og * 32;
  const int tid = threadIdx.x;
  const int ocl = tid & 31;
  const int tw = tid >> 5;
  const int m = n * 256 + th * 16 + tw;

  __shared__ float ys[32 * K4_PS];

  float Y[8][8];
  const size_t rb = (size_t)m * 128 + oc0 + ocl;
#pragma unroll
  for (int a = 0; a < 8; ++a)
#pragma unroll
    for (int b = 0; b < 8; ++b)
      Y[a][b] = bf2f(yt[(size_t)(a * 8 + b) * (M_ * 128) + rb]);

  float t2[4][8];
#pragma unroll
  for (int p = 0; p < 4; ++p)
#pragma unroll
    for (int b = 0; b < 8; ++b) {
      float v = 0.f;
#pragma unroll
      for (int a = 0; a < 8; ++a) {
        const float aa = AT[p][a];
        if (aa != 0.f) v += aa * Y[a][b];
      }
      t2[p][b] = v;
    }

  const float bv = bias[oc0 + ocl];
#pragma unroll
  for (int p = 0; p < 4; ++p) {
    float o[4];
#pragma unroll
    for (int q = 0; q < 4; ++q) {
      float v = 0.f;
#pragma unroll
      for (int b = 0; b < 8; ++b) {
        const float ab_ = AT[q][b];
        if (ab_ != 0.f) v += t2[p][b] * ab_;
      }
      o[q] = v + bv;
    }
    const float4 ov = {o[0], o[1], o[2], o[3]};
    *reinterpret_cast<float4*>(&ys[ocl * K4_PS + p * 64 + tw * 4]) = ov;
  }
  __syncthreads();

#pragma unroll
  for (int it = 0; it < 4; ++it) {
    const int idx = it * 512 + tid;
    const int f = idx & 15;
    const int p = (idx >> 4) & 3;
    const int oo = idx >> 6;
    const float4 v = *reinterpret_cast<const float4*>(&ys[oo * K4_PS + p * 64 + f * 4]);
    *reinterpret_cast<float4*>(
        y + ((size_t)((n * OC_ + oc0 + oo) * OW_) + th * 4 + p) * OW_ + f * 4) = v;
  }
}

// ---------------- launch ----------------
extern "C" void kernel_launch(void* const* d_in, const int* in_sizes, int n_in,
                              void* d_out, int out_size, void* d_ws, size_t ws_size,
                              hipStream_t stream) {
  (void)in_sizes; (void)n_in; (void)out_size; (void)ws_size;
  const float* x    = (const float*)d_in[0];
  const float* w    = (const float*)d_in[1];
  const float* bias = (const float*)d_in[2];
  float* y = (float*)d_out;

  char* ws = (char*)d_ws;
  unsigned short* xt = (unsigned short*)ws;                                 // 32 MiB
  unsigned short* yt = (unsigned short*)(ws + (size_t)32 * 1024 * 1024);    // 32 MiB
  unsigned short* wT = (unsigned short*)(ws + (size_t)64 * 1024 * 1024);    //  2 MiB

  hipLaunchKernelGGL(k_input_tf, dim3(8, 16, 8), dim3(256), 0, stream, x, xt);
  hipLaunchKernelGGL(k_wt, dim3((64 * 128 * 128) / 256), dim3(256), 0, stream, w, wT);
  hipLaunchKernelGGL(k_gemm, dim3(16, 1, 64), dim3(512), 0, stream, xt, wT, yt);
  hipLaunchKernelGGL(k_output_tf, dim3(4, 16, 8), dim3(512), 0, stream, yt, bias, y);
}

// Round 7
// 119.745 us; speedup vs baseline: 1.0922x; 1.0233x over previous
//
#include <hip/hip_runtime.h>

// ---------------- problem constants ----------------
#define N_    8
#define IC_   128
#define OC_   128
#define HW_   68
#define M_    2048           // total tiles = 8 * 16 * 16
#define OW_   64

constexpr float BT[8][8] = {
  {1.f, 0.f, -5.25f, 0.f, 5.25f, 0.f, -1.f, 0.f},
  {0.f, 1.f, 1.f, -4.25f, -4.25f, 1.f, 1.f, 0.f},
  {0.f, -1.f, 1.f, 4.25f, -4.25f, -1.f, 1.f, 0.f},
  {0.f, 0.5f, 0.25f, -2.5f, -1.25f, 2.f, 1.f, 0.f},
  {0.f, -0.5f, 0.25f, 2.5f, -1.25f, -2.f, 1.f, 0.f},
  {0.f, 2.f, 4.f, -2.5f, -5.f, 0.5f, 1.f, 0.f},
  {0.f, -2.f, 4.f, 2.5f, -5.f, -0.5f, 1.f, 0.f},
  {0.f, -1.f, 0.f, 5.25f, 0.f, -5.25f, 0.f, 1.f}
};
constexpr float AT[4][8] = {
  {1.f, 1.f, 1.f, 1.f, 1.f, 8.f, 8.f, 0.f},
  {0.f, 1.f, -1.f, 2.f, -2.f, 4.f, -4.f, 0.f},
  {0.f, 1.f, 1.f, 4.f, 4.f, 2.f, 2.f, 0.f},
  {0.f, 1.f, -1.f, 8.f, -8.f, 1.f, -1.f, 1.f}
};

__device__ __forceinline__ float bf2f(unsigned short u) {
  union { unsigned int i; float f; } v; v.i = ((unsigned int)u) << 16; return v.f;
}
__device__ __forceinline__ unsigned short f2bf(float f) {
  union { float f; unsigned int i; } v; v.f = f;
  unsigned int r = v.i + 0x7FFFu + ((v.i >> 16) & 1u);  // RNE
  return (unsigned short)(r >> 16);
}

typedef __attribute__((ext_vector_type(8))) short short8;
typedef __attribute__((ext_vector_type(4))) float f32x4;

// ---------------- K1: input transform (+ folded weight transform) ----------------
// grid (cg=4, th=0..16, n=8), block 512.
//  th<16 : input transform. Block covers 32 channels x 16 tw at one (n, th).
//          x staged in LDS as bf16 [32c][8r][72w-pitch-pad]; per-c pitch 580
//          shorts (290 words, 290%32=2 -> spread banks).
//          Writes: per (ab, tw): 32 contiguous c shorts = 64B segments.
//  th==16: weight transform wT[ab][oc][c] = bf16(w[oc][c][ab]) (32 blocks).
#define K1_CPITCH 580
__global__ __launch_bounds__(512) void k_in_wt(const float* __restrict__ x,
                                               const float* __restrict__ w,
                                               unsigned short* __restrict__ xt,
                                               unsigned short* __restrict__ wT) {
  const int cg = blockIdx.x, th = blockIdx.y, n = blockIdx.z;
  const int tid = threadIdx.x;

  if (th == 16) {
    // ---- weight transform: 32 blocks x 512 thr ----
    const int wb = n * 4 + cg;            // 0..31
    const int gtid = wb * 512 + tid;      // 0..16383
    for (int g = gtid; g < 262144; g += 16384) {
      const int ab4 = g & 15;             // lanes -> ab4 contiguous (coalesced read)
      const int c  = (g >> 4) & 127;
      const int oc = g >> 11;
      const float4 v = *reinterpret_cast<const float4*>(
          w + ((size_t)(oc * 128 + c)) * 64 + ab4 * 4);
      const float vv[4] = {v.x, v.y, v.z, v.w};
#pragma unroll
      for (int k = 0; k < 4; ++k)
        wT[(size_t)(ab4 * 4 + k) * 16384 + oc * 128 + c] = f2bf(vv[k]);
    }
    return;
  }

  // ---- input transform ----
  const int c0 = cg * 32;
  const int h0 = th * 4;
  __shared__ unsigned short xs[32 * K1_CPITCH];   // 36.25 KB

  // cooperative load: 32c * 8r * 17 float4, coalesced in 272B row runs
  for (int idx = tid; idx < 32 * 8 * 17; idx += 512) {
    const int ci = idx / 136;
    const int rem = idx - ci * 136;
    const int r = rem / 17;
    const int f = rem - r * 17;
    const float4 v = *reinterpret_cast<const float4*>(
        x + ((size_t)((n * IC_ + c0 + ci) * HW_ + h0 + r)) * HW_ + f * 4);
    ushort4 s;
    s.x = f2bf(v.x); s.y = f2bf(v.y); s.z = f2bf(v.z); s.w = f2bf(v.w);
    *reinterpret_cast<ushort4*>(&xs[ci * K1_CPITCH + r * 72 + f * 4]) = s;
  }
  __syncthreads();

  const int ct = tid & 31;      // channel lane
  const int tw = tid >> 5;      // tile column
  const unsigned short* xp = &xs[ct * K1_CPITCH];

  float t1[8][8];
#pragma unroll
  for (int a = 0; a < 8; ++a)
#pragma unroll
    for (int j = 0; j < 8; ++j) t1[a][j] = 0.f;

#pragma unroll
  for (int i = 0; i < 8; ++i) {
    const ushort4 u0 = *reinterpret_cast<const ushort4*>(xp + i * 72 + tw * 4);
    const ushort4 u1 = *reinterpret_cast<const ushort4*>(xp + i * 72 + tw * 4 + 4);
    const float r8[8] = {bf2f(u0.x), bf2f(u0.y), bf2f(u0.z), bf2f(u0.w),
                         bf2f(u1.x), bf2f(u1.y), bf2f(u1.z), bf2f(u1.w)};
#pragma unroll
    for (int a = 0; a < 8; ++a) {
      const float ba = BT[a][i];
      if (ba != 0.f) {
#pragma unroll
        for (int j = 0; j < 8; ++j) t1[a][j] += ba * r8[j];
      }
    }
  }

  const int m = n * 256 + th * 16 + tw;
  const size_t base = (size_t)m * 128 + c0 + ct;
#pragma unroll
  for (int a = 0; a < 8; ++a) {
#pragma unroll
    for (int b = 0; b < 8; ++b) {
      float v = 0.f;
#pragma unroll
      for (int j = 0; j < 8; ++j) {
        const float bb = BT[b][j];
        if (bb != 0.f) v += t1[a][j] * bb;
      }
      xt[(size_t)(a * 8 + b) * (M_ * 128) + base] = f2bf(v);   // 64B segments
    }
  }
}

// ---------------- K3: batched MFMA GEMM ----------------
// per ab: C[m][oc] = sum_c A[m][c] * Bt[oc][c];  A,Bt,C bf16 (f32 accum)
// BM=128 (grid.x=16), BN=128, K=128 fully staged. 512 thr = 8 waves (4m x 2n),
// wave tile 32m x 64oc. LDS 64KB -> 2 blocks/CU. XOR-swizzle via source addr.
__global__ __launch_bounds__(512) void k_gemm(const unsigned short* __restrict__ xt,
                                              const unsigned short* __restrict__ wT,
                                              unsigned short* __restrict__ yt) {
  const int ab = blockIdx.z;
  const int m0 = blockIdx.x * 128;
  const unsigned short* Ag = xt + (size_t)ab * (M_ * 128);
  const unsigned short* Bg = wT + (size_t)ab * (128 * 128);
  unsigned short* Cg = yt + (size_t)ab * (M_ * 128);

  __shared__ unsigned short As[128 * 128];   // 32 KB, row=m
  __shared__ unsigned short Bs[128 * 128];   // 32 KB, row=oc

  const int tid = threadIdx.x;
  const int lane = tid & 63;
  const int wv = tid >> 6;

#pragma unroll
  for (int i = 0; i < 4; ++i) {
    const int inst = wv * 4 + i;
    const int r = inst * 4 + (lane >> 4);
    const int j = (lane & 15) ^ (r & 7);
    __builtin_amdgcn_global_load_lds(
        (const __attribute__((address_space(1))) void*)(Ag + (size_t)(m0 + r) * 128 + j * 8),
        (__attribute__((address_space(3))) void*)(As + inst * 512), 16, 0, 0);
  }
#pragma unroll
  for (int i = 0; i < 4; ++i) {
    const int inst = wv * 4 + i;
    const int r = inst * 4 + (lane >> 4);
    const int j = (lane & 15) ^ (r & 7);
    __builtin_amdgcn_global_load_lds(
        (const __attribute__((address_space(1))) void*)(Bg + (size_t)r * 128 + j * 8),
        (__attribute__((address_space(3))) void*)(Bs + inst * 512), 16, 0, 0);
  }
  __syncthreads();

  const int wm = wv >> 1, wn = wv & 1;
  const int m_base = wm * 32;
  const int oc_base = wn * 64;
  const int lr = lane & 15;
  const int lg = lane >> 4;

  f32x4 acc[2][4];
#pragma unroll
  for (int mi = 0; mi < 2; ++mi)
#pragma unroll
    for (int ni = 0; ni < 4; ++ni) acc[mi][ni] = (f32x4){0.f, 0.f, 0.f, 0.f};

#pragma unroll
  for (int kk = 0; kk < 4; ++kk) {
    short8 af[2], bf[4];
#pragma unroll
    for (int mi = 0; mi < 2; ++mi) {
      const int row = m_base + mi * 16 + lr;
      const int chunk = (kk * 4 + lg) ^ (row & 7);
      af[mi] = *reinterpret_cast<const short8*>(&As[row * 128 + chunk * 8]);
    }
#pragma unroll
    for (int ni = 0; ni < 4; ++ni) {
      const int row = oc_base + ni * 16 + lr;
      const int chunk = (kk * 4 + lg) ^ (row & 7);
      bf[ni] = *reinterpret_cast<const short8*>(&Bs[row * 128 + chunk * 8]);
    }
#pragma unroll
    for (int mi = 0; mi < 2; ++mi)
#pragma unroll
      for (int ni = 0; ni < 4; ++ni)
        acc[mi][ni] = __builtin_amdgcn_mfma_f32_16x16x32_bf16(af[mi], bf[ni], acc[mi][ni], 0, 0, 0);
  }

#pragma unroll
  for (int mi = 0; mi < 2; ++mi) {
#pragma unroll
    for (int ni = 0; ni < 4; ++ni) {
#pragma unroll
      for (int j = 0; j < 4; ++j) {
        const int row = m0 + m_base + mi * 16 + lg * 4 + j;
        const int col = oc_base + ni * 16 + lr;
        Cg[(size_t)row * 128 + col] = f2bf(acc[mi][ni][j]);
      }
    }
  }
}

// ---------------- K4: output transform + bias ----------------
// grid (og=2, thw=32, n=8), block 512 = (tw 8) x (ocl 64).
// Reads yt[ab][m][oc0+ocl]: 64 contiguous shorts per wave = 128B lines.
// Stage y in LDS with XOR swizzle (conflict-free b128), coalesced 128B writes.
__global__ __launch_bounds__(512) void k_output_tf(const unsigned short* __restrict__ yt,
                                                   const float* __restrict__ bias,
                                                   float* __restrict__ y) {
  const int og = blockIdx.x;     // 0..1
  const int thw = blockIdx.y;    // 0..31
  const int n = blockIdx.z;      // 0..7
  const int oc0 = og * 64;
  const int tid = threadIdx.x;
  const int ocl = tid & 63;
  const int tw = tid >> 6;       // 0..7
  const int m = n * 256 + thw * 8 + tw;
  const int th = thw >> 1;
  const int wq = thw & 1;        // which 32-col half of the row

  __shared__ float ys[64 * 128]; // 32 KB

  float Y[8][8];
  const size_t rb = (size_t)m * 128 + oc0 + ocl;
#pragma unroll
  for (int a = 0; a < 8; ++a)
#pragma unroll
    for (int b = 0; b < 8; ++b)
      Y[a][b] = bf2f(yt[(size_t)(a * 8 + b) * (M_ * 128) + rb]);

  float t2[4][8];
#pragma unroll
  for (int p = 0; p < 4; ++p)
#pragma unroll
    for (int b = 0; b < 8; ++b) {
      float v = 0.f;
#pragma unroll
      for (int a = 0; a < 8; ++a) {
        const float aa = AT[p][a];
        if (aa != 0.f) v += aa * Y[a][b];
      }
      t2[p][b] = v;
    }

  const float bv = bias[oc0 + ocl];
#pragma unroll
  for (int p = 0; p < 4; ++p) {
    float o[4];
#pragma unroll
    for (int q = 0; q < 4; ++q) {
      float v = 0.f;
#pragma unroll
      for (int b = 0; b < 8; ++b) {
        const float ab_ = AT[q][b];
        if (ab_ != 0.f) v += t2[p][b] * ab_;
      }
      o[q] = v + bv;
    }
    const float4 ov = {o[0], o[1], o[2], o[3]};
    *reinterpret_cast<float4*>(&ys[ocl * 128 + p * 32 + ((tw ^ (ocl & 7)) * 4)]) = ov;
  }
  __syncthreads();

  // write-out: 64 oc * 4 p * 8 float4 = 2048 float4; 128B contiguous per (oc,p)
#pragma unroll
  for (int it = 0; it < 4; ++it) {
    const int idx = it * 512 + tid;
    const int f = idx & 7;
    const int p = (idx >> 3) & 3;
    const int row = idx >> 5;    // oc-local 0..63
    const float4 v = *reinterpret_cast<const float4*>(
        &ys[row * 128 + p * 32 + ((f ^ (row & 7)) * 4)]);
    *reinterpret_cast<float4*>(
        y + (((size_t)(n * OC_ + oc0 + row) * OW_) + th * 4 + p) * OW_ + wq * 32 + f * 4) = v;
  }
}

// ---------------- launch ----------------
extern "C" void kernel_launch(void* const* d_in, const int* in_sizes, int n_in,
                              void* d_out, int out_size, void* d_ws, size_t ws_size,
                              hipStream_t stream) {
  (void)in_sizes; (void)n_in; (void)out_size; (void)ws_size;
  const float* x    = (const float*)d_in[0];
  const float* w    = (const float*)d_in[1];
  const float* bias = (const float*)d_in[2];
  float* y = (float*)d_out;

  char* ws = (char*)d_ws;
  unsigned short* xt = (unsigned short*)ws;                                 // 32 MiB
  unsigned short* yt = (unsigned short*)(ws + (size_t)32 * 1024 * 1024);    // 32 MiB
  unsigned short* wT = (unsigned short*)(ws + (size_t)64 * 1024 * 1024);    //  2 MiB

  hipLaunchKernelGGL(k_in_wt, dim3(4, 17, 8), dim3(512), 0, stream, x, w, xt, wT);
  hipLaunchKernelGGL(k_gemm, dim3(16, 1, 64), dim3(512), 0, stream, xt, wT, yt);
  hipLaunchKernelGGL(k_output_tf, dim3(2, 32, 8), dim3(512), 0, stream, yt, bias, y);
}

// Round 9
// 119.559 us; speedup vs baseline: 1.0939x; 1.0015x over previous
//
#include <hip/hip_runtime.h>

// ---------------- problem constants ----------------
#define N_    8
#define IC_   128
#define OC_   128
#define HW_   68
#define M_    2048           // total tiles = 8 * 16 * 16
#define OW_   64

constexpr float BT[8][8] = {
  {1.f, 0.f, -5.25f, 0.f, 5.25f, 0.f, -1.f, 0.f},
  {0.f, 1.f, 1.f, -4.25f, -4.25f, 1.f, 1.f, 0.f},
  {0.f, -1.f, 1.f, 4.25f, -4.25f, -1.f, 1.f, 0.f},
  {0.f, 0.5f, 0.25f, -2.5f, -1.25f, 2.f, 1.f, 0.f},
  {0.f, -0.5f, 0.25f, 2.5f, -1.25f, -2.f, 1.f, 0.f},
  {0.f, 2.f, 4.f, -2.5f, -5.f, 0.5f, 1.f, 0.f},
  {0.f, -2.f, 4.f, 2.5f, -5.f, -0.5f, 1.f, 0.f},
  {0.f, -1.f, 0.f, 5.25f, 0.f, -5.25f, 0.f, 1.f}
};
constexpr float AT[4][8] = {
  {1.f, 1.f, 1.f, 1.f, 1.f, 8.f, 8.f, 0.f},
  {0.f, 1.f, -1.f, 2.f, -2.f, 4.f, -4.f, 0.f},
  {0.f, 1.f, 1.f, 4.f, 4.f, 2.f, 2.f, 0.f},
  {0.f, 1.f, -1.f, 8.f, -8.f, 1.f, -1.f, 1.f}
};

__device__ __forceinline__ float bf2f(unsigned short u) {
  union { unsigned int i; float f; } v; v.i = ((unsigned int)u) << 16; return v.f;
}
__device__ __forceinline__ unsigned short f2bf(float f) {
  union { float f; unsigned int i; } v; v.f = f;
  unsigned int r = v.i + 0x7FFFu + ((v.i >> 16) & 1u);  // RNE
  return (unsigned short)(r >> 16);
}

typedef __attribute__((ext_vector_type(8))) short short8;
typedef __attribute__((ext_vector_type(4))) float f32x4;

// ---------------- K1: input transform (+ folded weight transform) ----------------
// (unchanged from round 7 — passed)
#define K1_CPITCH 580
__global__ __launch_bounds__(512) void k_in_wt(const float* __restrict__ x,
                                               const float* __restrict__ w,
                                               unsigned short* __restrict__ xt,
                                               unsigned short* __restrict__ wT) {
  const int cg = blockIdx.x, th = blockIdx.y, n = blockIdx.z;
  const int tid = threadIdx.x;

  if (th == 16) {
    const int wb = n * 4 + cg;            // 0..31
    const int gtid = wb * 512 + tid;      // 0..16383
    for (int g = gtid; g < 262144; g += 16384) {
      const int ab4 = g & 15;
      const int c  = (g >> 4) & 127;
      const int oc = g >> 11;
      const float4 v = *reinterpret_cast<const float4*>(
          w + ((size_t)(oc * 128 + c)) * 64 + ab4 * 4);
      const float vv[4] = {v.x, v.y, v.z, v.w};
#pragma unroll
      for (int k = 0; k < 4; ++k)
        wT[(size_t)(ab4 * 4 + k) * 16384 + oc * 128 + c] = f2bf(vv[k]);
    }
    return;
  }

  const int c0 = cg * 32;
  const int h0 = th * 4;
  __shared__ unsigned short xs[32 * K1_CPITCH];   // 36.25 KB

  for (int idx = tid; idx < 32 * 8 * 17; idx += 512) {
    const int ci = idx / 136;
    const int rem = idx - ci * 136;
    const int r = rem / 17;
    const int f = rem - r * 17;
    const float4 v = *reinterpret_cast<const float4*>(
        x + ((size_t)((n * IC_ + c0 + ci) * HW_ + h0 + r)) * HW_ + f * 4);
    ushort4 s;
    s.x = f2bf(v.x); s.y = f2bf(v.y); s.z = f2bf(v.z); s.w = f2bf(v.w);
    *reinterpret_cast<ushort4*>(&xs[ci * K1_CPITCH + r * 72 + f * 4]) = s;
  }
  __syncthreads();

  const int ct = tid & 31;
  const int tw = tid >> 5;
  const unsigned short* xp = &xs[ct * K1_CPITCH];

  float t1[8][8];
#pragma unroll
  for (int a = 0; a < 8; ++a)
#pragma unroll
    for (int j = 0; j < 8; ++j) t1[a][j] = 0.f;

#pragma unroll
  for (int i = 0; i < 8; ++i) {
    const ushort4 u0 = *reinterpret_cast<const ushort4*>(xp + i * 72 + tw * 4);
    const ushort4 u1 = *reinterpret_cast<const ushort4*>(xp + i * 72 + tw * 4 + 4);
    const float r8[8] = {bf2f(u0.x), bf2f(u0.y), bf2f(u0.z), bf2f(u0.w),
                         bf2f(u1.x), bf2f(u1.y), bf2f(u1.z), bf2f(u1.w)};
#pragma unroll
    for (int a = 0; a < 8; ++a) {
      const float ba = BT[a][i];
      if (ba != 0.f) {
#pragma unroll
        for (int j = 0; j < 8; ++j) t1[a][j] += ba * r8[j];
      }
    }
  }

  const int m = n * 256 + th * 16 + tw;
  const size_t base = (size_t)m * 128 + c0 + ct;
#pragma unroll
  for (int a = 0; a < 8; ++a) {
#pragma unroll
    for (int b = 0; b < 8; ++b) {
      float v = 0.f;
#pragma unroll
      for (int j = 0; j < 8; ++j) {
        const float bb = BT[b][j];
        if (bb != 0.f) v += t1[a][j] * bb;
      }
      xt[(size_t)(a * 8 + b) * (M_ * 128) + base] = f2bf(v);
    }
  }
}

// ---------------- K3: batched MFMA GEMM + a-fold ----------------
// grid (mb=32 [BM=64], b=8), block 512 = 8 waves (4m x 2n), wave tile 16m x 64oc.
// Loops a=0..7: GEMM for ab=a*8+b (K=128 staged in LDS), folds into
// zacc[p] += AT[p][a] * acc. Writes Z[(p*8+b)][m][oc] bf16 (16.8 MB total).
__global__ __launch_bounds__(512) void k_gemm_z(const unsigned short* __restrict__ xt,
                                                const unsigned short* __restrict__ wT,
                                                unsigned short* __restrict__ Z) {
  const int b  = blockIdx.y;          // 0..7
  const int m0 = blockIdx.x * 64;

  __shared__ unsigned short As[64 * 128];    // 16 KB, row=m
  __shared__ unsigned short Bs[128 * 128];   // 32 KB, row=oc

  const int tid = threadIdx.x;
  const int lane = tid & 63;
  const int wv = tid >> 6;
  const int lr = lane & 15;
  const int lg = lane >> 4;
  const int wm = wv >> 1, wn = wv & 1;
  const int m_base = wm * 16;
  const int oc_base = wn * 64;

  f32x4 zacc[4][4];                   // [p][ni]
#pragma unroll
  for (int p = 0; p < 4; ++p)
#pragma unroll
    for (int ni = 0; ni < 4; ++ni) zacc[p][ni] = (f32x4){0.f, 0.f, 0.f, 0.f};

#pragma unroll
  for (int a = 0; a < 8; ++a) {
    const int ab = a * 8 + b;
    const unsigned short* Ag = xt + (size_t)ab * (M_ * 128) + (size_t)m0 * 128;
    const unsigned short* Bg = wT + (size_t)ab * 16384;

    // stage A: 16 insts (2/wave); B: 32 insts (4/wave). XOR-swizzled source.
#pragma unroll
    for (int i = 0; i < 2; ++i) {
      const int inst = wv * 2 + i;
      const int r = inst * 4 + lg;
      const int j = lr ^ (r & 7);
      __builtin_amdgcn_global_load_lds(
          (const __attribute__((address_space(1))) void*)(Ag + (size_t)r * 128 + j * 8),
          (__attribute__((address_space(3))) void*)(As + inst * 512), 16, 0, 0);
    }
#pragma unroll
    for (int i = 0; i < 4; ++i) {
      const int inst = wv * 4 + i;
      const int r = inst * 4 + lg;
      const int j = lr ^ (r & 7);
      __builtin_amdgcn_global_load_lds(
          (const __attribute__((address_space(1))) void*)(Bg + (size_t)r * 128 + j * 8),
          (__attribute__((address_space(3))) void*)(Bs + inst * 512), 16, 0, 0);
    }
    __syncthreads();

    f32x4 acc[4];
#pragma unroll
    for (int ni = 0; ni < 4; ++ni) acc[ni] = (f32x4){0.f, 0.f, 0.f, 0.f};

#pragma unroll
    for (int kk = 0; kk < 4; ++kk) {
      const int arow = m_base + lr;
      const short8 af = *reinterpret_cast<const short8*>(
          &As[arow * 128 + ((kk * 4 + lg) ^ (arow & 7)) * 8]);
      short8 bf[4];
#pragma unroll
      for (int ni = 0; ni < 4; ++ni) {
        const int brow = oc_base + ni * 16 + lr;
        bf[ni] = *reinterpret_cast<const short8*>(
            &Bs[brow * 128 + ((kk * 4 + lg) ^ (brow & 7)) * 8]);
      }
#pragma unroll
      for (int ni = 0; ni < 4; ++ni)
        acc[ni] = __builtin_amdgcn_mfma_f32_16x16x32_bf16(af, bf[ni], acc[ni], 0, 0, 0);
    }

    // fold a: zacc[p] += AT[p][a] * acc   (compile-time zero-skip)
#pragma unroll
    for (int p = 0; p < 4; ++p) {
      const float w_ = AT[p][a];
      if (w_ != 0.f) {
#pragma unroll
        for (int ni = 0; ni < 4; ++ni)
#pragma unroll
          for (int j = 0; j < 4; ++j)
            zacc[p][ni][j] += w_ * acc[ni][j];
      }
    }
    __syncthreads();
  }

  // ---- write Z[(p*8+b)][m][oc] bf16; C mapping: col=lr, row=lg*4+j ----
#pragma unroll
  for (int p = 0; p < 4; ++p) {
    unsigned short* Zp = Z + (size_t)(p * 8 + b) * (M_ * 128);
#pragma unroll
    for (int ni = 0; ni < 4; ++ni) {
#pragma unroll
      for (int j = 0; j < 4; ++j) {
        const int row = m0 + m_base + lg * 4 + j;
        const int col = oc_base + ni * 16 + lr;
        Zp[(size_t)row * 128 + col] = f2bf(zacc[p][ni][j]);
      }
    }
  }
}

// ---------------- K4: output b-fold + bias ----------------
// grid (og=2, thw=32, n=8), block 512 = (tw 8) x (ocl 64).
// Reads Z[(p*8+b)][m][oc0+ocl] (32 slices, 128B lines), folds b, writes y.
__global__ __launch_bounds__(512) void k_output_z(const unsigned short* __restrict__ Z,
                                                  const float* __restrict__ bias,
                                                  float* __restrict__ y) {
  const int og = blockIdx.x;     // 0..1
  const int thw = blockIdx.y;    // 0..31
  const int n = blockIdx.z;      // 0..7
  const int oc0 = og * 64;
  const int tid = threadIdx.x;
  const int ocl = tid & 63;
  const int tw = tid >> 6;       // 0..7
  const int m = n * 256 + thw * 8 + tw;
  const int th = thw >> 1;
  const int wq = thw & 1;

  __shared__ float ys[64 * 128]; // 32 KB

  float t2[4][8];
  const size_t rb = (size_t)m * 128 + oc0 + ocl;
#pragma unroll
  for (int p = 0; p < 4; ++p)
#pragma unroll
    for (int b = 0; b < 8; ++b)
      t2[p][b] = bf2f(Z[(size_t)(p * 8 + b) * (M_ * 128) + rb]);

  const float bv = bias[oc0 + ocl];
#pragma unroll
  for (int p = 0; p < 4; ++p) {
    float o[4];
#pragma unroll
    for (int q = 0; q < 4; ++q) {
      float v = 0.f;
#pragma unroll
      for (int b = 0; b < 8; ++b) {
        const float ab_ = AT[q][b];
        if (ab_ != 0.f) v += t2[p][b] * ab_;
      }
      o[q] = v + bv;
    }
    const float4 ov = {o[0], o[1], o[2], o[3]};
    *reinterpret_cast<float4*>(&ys[ocl * 128 + p * 32 + ((tw ^ (ocl & 7)) * 4)]) = ov;
  }
  __syncthreads();

#pragma unroll
  for (int it = 0; it < 4; ++it) {
    const int idx = it * 512 + tid;
    const int f = idx & 7;
    const int p = (idx >> 3) & 3;
    const int row = idx >> 5;    // oc-local 0..63
    const float4 v = *reinterpret_cast<const float4*>(
        &ys[row * 128 + p * 32 + ((f ^ (row & 7)) * 4)]);
    *reinterpret_cast<float4*>(
        y + (((size_t)(n * OC_ + oc0 + row) * OW_) + th * 4 + p) * OW_ + wq * 32 + f * 4) = v;
  }
}

// ---------------- launch ----------------
extern "C" void kernel_launch(void* const* d_in, const int* in_sizes, int n_in,
                              void* d_out, int out_size, void* d_ws, size_t ws_size,
                              hipStream_t stream) {
  (void)in_sizes; (void)n_in; (void)out_size; (void)ws_size;
  const float* x    = (const float*)d_in[0];
  const float* w    = (const float*)d_in[1];
  const float* bias = (const float*)d_in[2];
  float* y = (float*)d_out;

  char* ws = (char*)d_ws;
  unsigned short* xt = (unsigned short*)ws;                                 // 32 MiB
  unsigned short* Zb = (unsigned short*)(ws + (size_t)32 * 1024 * 1024);    // 16 MiB (32 slices)
  unsigned short* wT = (unsigned short*)(ws + (size_t)64 * 1024 * 1024);    //  2 MiB

  hipLaunchKernelGGL(k_in_wt, dim3(4, 17, 8), dim3(512), 0, stream, x, w, xt, wT);
  hipLaunchKernelGGL(k_gemm_z, dim3(32, 8), dim3(512), 0, stream, xt, wT, Zb);
  hipLaunchKernelGGL(k_output_z, dim3(2, 32, 8), dim3(512), 0, stream, Zb, bias, y);
}